// Round 4
// baseline (397.822 us; speedup 1.0000x reference)
//
#include <hip/hip_runtime.h>
#include <cstdint>

#define M_DIM 8192   // B*S = 4*2048
#define N_DIM 4096   // D_OUT
#define K_DIM 4096   // D_IN
#define NT    32     // K_DIM / 128 K-tiles

typedef int i32x4  __attribute__((ext_vector_type(4)));
typedef int i32x16 __attribute__((ext_vector_type(16)));

// async global->LDS, 16B per lane. LDS dest is wave-uniform base; HW
// scatters lane i to base + i*16. Global source IS per-lane (swizzle there).
__device__ __forceinline__ void gload_lds16(const void* g, void* l) {
  __builtin_amdgcn_global_load_lds(
      (const __attribute__((address_space(1))) unsigned int*)(uintptr_t)g,
      (__attribute__((address_space(3))) unsigned int*)(uintptr_t)l,
      16, 0, 0);
}

// ---------------- prep (unchanged) ----------------
__global__ __launch_bounds__(256) void prep_kernel(
    const float* __restrict__ x, const int* __restrict__ q,
    signed char* __restrict__ xq, signed char* __restrict__ wq8,
    float* __restrict__ sx, float* __restrict__ si) {
  const int tid  = threadIdx.x;
  const int lane = tid & 63;
  const int wv   = tid >> 6;
  if (blockIdx.x < 2048) {
    const int row = blockIdx.x * 4 + wv;
    const float* xr = x + (size_t)row * K_DIM;
    signed char* xo = xq + (size_t)row * K_DIM;
    float4 v[16];
    float amax = 0.f;
#pragma unroll
    for (int j = 0; j < 16; ++j) {
      v[j] = *(const float4*)(xr + j * 256 + lane * 4);
      amax = fmaxf(amax, fmaxf(fmaxf(fabsf(v[j].x), fabsf(v[j].y)),
                               fmaxf(fabsf(v[j].z), fabsf(v[j].w))));
    }
#pragma unroll
    for (int off = 32; off > 0; off >>= 1)
      amax = fmaxf(amax, __shfl_xor(amax, off, 64));
    const float inv = amax > 0.f ? 127.f / amax : 0.f;
    int isum = 0;
#pragma unroll
    for (int j = 0; j < 16; ++j) {
      int ix = __float2int_rn(v[j].x * inv);
      int iy = __float2int_rn(v[j].y * inv);
      int iz = __float2int_rn(v[j].z * inv);
      int iw = __float2int_rn(v[j].w * inv);
      isum += ix + iy + iz + iw;
      char4 o; o.x = (char)ix; o.y = (char)iy; o.z = (char)iz; o.w = (char)iw;
      *(char4*)(xo + j * 256 + lane * 4) = o;
    }
#pragma unroll
    for (int off = 32; off > 0; off >>= 1)
      isum += __shfl_xor(isum, off, 64);
    if (lane == 0) {
      sx[row] = amax * (1.f / 127.f);
      si[row] = (float)isum;
    }
  } else {
    const int bid = blockIdx.x - 2048;               // 0..1023
    const size_t total  = (size_t)N_DIM * K_DIM;     // 16.78M ints
    const size_t stride = (size_t)1024 * 4096;       // ints per sweep
    for (size_t base = (size_t)bid * 4096; base < total; base += stride) {
#pragma unroll
      for (int u = 0; u < 4; ++u) {
        const size_t idx = base + (size_t)u * 1024 + tid * 4;
        int4 w = *(const int4*)(q + idx);
        char4 o; o.x = (char)w.x; o.y = (char)w.y; o.z = (char)w.z; o.w = (char)w.w;
        *(char4*)(wq8 + idx) = o;
      }
    }
  }
}

// ---------------- GEMM i8, 256x256 tile, BK=128, 8 waves ------------------
// Round-1's 4-phase schedule (best measured) with mfma_i32_32x32x32_i8:
// +12% shape ceiling (4404 vs 3944 TOPS) and HALF the MFMA instruction
// count per tile (32 vs 64 per wave), same LDS traffic, same swizzle.
//
// vmcnt ledger (stage order per tile: B00,B01 | B10,B11 | A00,A10 | A01,A11):
//   tile entry: 8 outstanding.  ph1 vmcnt(2): B*4 + A-c0*2 landed.
//   ph3 vmcnt(4): A-c1*2 landed (4 newest = B of t+1).  Never 0 mid-loop.
// Stage-into-buf^1 at phase top is ordered after two barriers since the last
// reads of that region -> no overwrite race.
__global__ __launch_bounds__(512) void qlinear_gemm_kernel(
    const signed char* __restrict__ A,     // [M][K] int8
    const signed char* __restrict__ Bm,    // [N][K] int8
    const float* __restrict__ sx,          // [M]
    const float* __restrict__ si,          // [M]
    const float* __restrict__ scale_p, const float* __restrict__ zp_p,
    const float* __restrict__ bias,        // [N]
    float* __restrict__ out) {             // [M][N] fp32
  __shared__ signed char sA[2][2][16384];  // 64 KB
  __shared__ signed char sB[2][2][16384];  // 64 KB

  const int tid  = threadIdx.x;
  const int lane = tid & 63;
  const int w    = tid >> 6;     // wave 0..7
  const int wr   = w >> 2;       // 0..1 : wave row (M), owns A-half wr
  const int wc   = w & 3;        // 0..3 : wave col (N)

  // XCD-chunked swizzle (bijective: 512 % 8 == 0)
  const int bid = blockIdx.x;                  // 0..511
  const int swz = (bid & 7) * 64 + (bid >> 3);
  const int bm  = (swz >> 4) * 256;            // 32 M-rows
  const int bn  = (swz & 15) * 256;            // 16 N-cols

  // ---- staging: per-lane pre-swizzled global source ----
  const int srow = lane >> 3;              // row within 8-row wave slab
  const int cg   = (lane & 7) ^ srow;      // global 16B chunk for this lane
  const signed char* aG = A  + (size_t)(bm + w * 8 + srow) * K_DIM + cg * 16;
  const signed char* bG = Bm + (size_t)(bn + w * 8 + srow) * K_DIM + cg * 16;
  const int dwoff = w * 1024;              // wave-uniform LDS slab offset

#define STG_A(dst, h, c, t) \
  gload_lds16(aG + (size_t)((h) * 128 + (c) * 64) * K_DIM + (size_t)(t) * 128, \
              (dst) + (h) * 16384 + (c) * 8192 + dwoff)
#define STG_B(dst, h, c, t) \
  gload_lds16(bG + (size_t)((h) * 128 + (c) * 64) * K_DIM + (size_t)(t) * 128, \
              (dst) + (h) * 16384 + (c) * 8192 + dwoff)

  // read-side swizzled byte offsets per 32-byte k-substep (ks=0..3):
  // row_local = lane&31 (row&7 == lane&7), global chunk = ks*2 + (lane>>5)
  int loff[4];
#pragma unroll
  for (int ks = 0; ks < 4; ++ks)
    loff[ks] = (lane & 31) * 128 + (((ks * 2 + (lane >> 5)) ^ (lane & 7)) * 16);

  i32x16 acc[4][2] = {};   // [m-subtile 32rows][n-subtile 32cols]

  // ---- prologue: stage tile 0 in steady-state issue order ----
  {
    signed char* dA = &sA[0][0][0];
    signed char* dB = &sB[0][0][0];
    STG_B(dB, 0, 0, 0); STG_B(dB, 0, 1, 0);
    STG_B(dB, 1, 0, 0); STG_B(dB, 1, 1, 0);
    STG_A(dA, 0, 0, 0); STG_A(dA, 1, 0, 0);
    STG_A(dA, 0, 1, 0); STG_A(dA, 1, 1, 0);
  }

  for (int t = 0; t < NT; ++t) {
    const int buf = t & 1;
    const signed char* pA = &sA[buf][wr][0];
    const signed char* pB = &sB[buf][wc >> 1][0] + (wc & 1) * 8192;
    signed char* nA = &sA[buf ^ 1][0][0];
    signed char* nB = &sB[buf ^ 1][0][0];
    const bool st = (t + 1) < NT;
    const int tn = t + 1;

    i32x4 afr[2][4], afr2[2][4], bfr0[4], bfr1[4];

    // ---------- phase 1 : mh0 x n0 ----------
    asm volatile("s_waitcnt vmcnt(2)" ::: "memory");   // B*4 + A-c0*2 landed
    if (st) { STG_B(nB, 0, 0, tn); STG_B(nB, 0, 1, tn); }
    __builtin_amdgcn_s_barrier();
#pragma unroll
    for (int m = 0; m < 2; ++m)
#pragma unroll
      for (int ks = 0; ks < 4; ++ks)
        afr[m][ks] = *(const i32x4*)(pA + m * 4096 + loff[ks]);
#pragma unroll
    for (int ks = 0; ks < 4; ++ks)
      bfr0[ks] = *(const i32x4*)(pB + loff[ks]);
    __builtin_amdgcn_s_setprio(1);
#pragma unroll
    for (int m = 0; m < 2; ++m)
#pragma unroll
      for (int ks = 0; ks < 4; ++ks)
        acc[m][0] = __builtin_amdgcn_mfma_i32_32x32x32_i8(
            afr[m][ks], bfr0[ks], acc[m][0], 0, 0, 0);
    __builtin_amdgcn_s_setprio(0);

    // ---------- phase 2 : mh0 x n1 ----------
    if (st) { STG_B(nB, 1, 0, tn); STG_B(nB, 1, 1, tn); }
    __builtin_amdgcn_s_barrier();
#pragma unroll
    for (int ks = 0; ks < 4; ++ks)
      bfr1[ks] = *(const i32x4*)(pB + 4096 + loff[ks]);
    __builtin_amdgcn_s_setprio(1);
#pragma unroll
    for (int m = 0; m < 2; ++m)
#pragma unroll
      for (int ks = 0; ks < 4; ++ks)
        acc[m][1] = __builtin_amdgcn_mfma_i32_32x32x32_i8(
            afr[m][ks], bfr1[ks], acc[m][1], 0, 0, 0);
    __builtin_amdgcn_s_setprio(0);

    // ---------- phase 3 : mh1 x n0 ----------
    if (st) asm volatile("s_waitcnt vmcnt(4)" ::: "memory");  // A-c1 of t landed
    else    asm volatile("s_waitcnt vmcnt(0)" ::: "memory");  // last tile drain
    if (st) { STG_A(nA, 0, 0, tn); STG_A(nA, 1, 0, tn); }
    __builtin_amdgcn_s_barrier();
#pragma unroll
    for (int m = 0; m < 2; ++m)
#pragma unroll
      for (int ks = 0; ks < 4; ++ks)
        afr2[m][ks] = *(const i32x4*)(pA + 8192 + m * 4096 + loff[ks]);
    __builtin_amdgcn_s_setprio(1);
#pragma unroll
    for (int m = 0; m < 2; ++m)
#pragma unroll
      for (int ks = 0; ks < 4; ++ks)
        acc[2 + m][0] = __builtin_amdgcn_mfma_i32_32x32x32_i8(
            afr2[m][ks], bfr0[ks], acc[2 + m][0], 0, 0, 0);
    __builtin_amdgcn_s_setprio(0);

    // ---------- phase 4 : mh1 x n1 ----------
    if (st) { STG_A(nA, 0, 1, tn); STG_A(nA, 1, 1, tn); }
    __builtin_amdgcn_s_barrier();
    __builtin_amdgcn_s_setprio(1);
#pragma unroll
    for (int m = 0; m < 2; ++m)
#pragma unroll
      for (int ks = 0; ks < 4; ++ks)
        acc[2 + m][1] = __builtin_amdgcn_mfma_i32_32x32x32_i8(
            afr2[m][ks], bfr1[ks], acc[2 + m][1], 0, 0, 0);
    __builtin_amdgcn_s_setprio(0);
  }
#undef STG_A
#undef STG_B

  // ---------- epilogue ----------
  const float scale = *scale_p;
  const float zp    = *zp_p;
  // 32x32 C/D layout: col = lane&31, row = (r&3) + 8*(r>>2) + 4*(lane>>5)
#pragma unroll
  for (int m = 0; m < 4; ++m) {
    const int rbase = bm + wr * 128 + m * 32 + 4 * (lane >> 5);
    float am[16], cm[16];
#pragma unroll
    for (int r = 0; r < 16; ++r) {
      const int row = rbase + (r & 3) + 8 * (r >> 2);
      am[r] = scale * sx[row];
      cm[r] = -am[r] * zp * si[row];
    }
#pragma unroll
    for (int n = 0; n < 2; ++n) {
      const int gn = bn + wc * 64 + n * 32 + (lane & 31);
      const float bb = bias[gn];
#pragma unroll
      for (int r = 0; r < 16; ++r) {
        const int row = rbase + (r & 3) + 8 * (r >> 2);
        out[(size_t)row * N_DIM + gn] =
            am[r] * (float)acc[m][n][r] + cm[r] + bb;
      }
    }
  }
}

extern "C" void kernel_launch(void* const* d_in, const int* in_sizes, int n_in,
                              void* d_out, int out_size, void* d_ws, size_t ws_size,
                              hipStream_t stream) {
  const float* x     = (const float*)d_in[0];
  const int*   wq    = (const int*)d_in[1];
  const float* scale = (const float*)d_in[2];
  const float* zp    = (const float*)d_in[3];
  const float* bias  = (const float*)d_in[4];
  float* out = (float*)d_out;

  // ws: xq (8192*4096 i8) | wq8 (4096*4096 i8) | sx | si
  signed char* xq  = (signed char*)d_ws;
  signed char* wq8 = xq + (size_t)M_DIM * K_DIM;
  float* sx = (float*)(wq8 + (size_t)N_DIM * K_DIM);
  float* si = sx + M_DIM;

  prep_kernel<<<3072, 256, 0, stream>>>(x, wq, xq, wq8, sx, si);
  qlinear_gemm_kernel<<<512, 512, 0, stream>>>(xq, wq8, sx, si, scale, zp, bias, out);
}